// Round 7
// baseline (466.503 us; speedup 1.0000x reference)
//
#include <hip/hip_runtime.h>
#include <math.h>

#define FLT_BIG 3.402823466e38f
typedef unsigned int uint;
typedef unsigned short ushort;
typedef __attribute__((ext_vector_type(8))) short short8;   // 8 bf16 (4 VGPRs)
typedef __attribute__((ext_vector_type(4))) float floatx4;  // MFMA C/D frag

__device__ inline float bl(uint u) { return __uint_as_float(u << 16); }
__device__ inline float bh(uint u) { return __uint_as_float(u & 0xffff0000u); }
__device__ inline ushort f2bf(float f) {  // RNE
    uint u = __float_as_uint(f);
    return (ushort)((u + 0x7fffu + ((u >> 16) & 1u)) >> 16);
}
__device__ inline float dot4(float4 a, float4 b) {
    return a.x * b.x + a.y * b.y + a.z * b.z + a.w * b.w;
}

// ---------------------------------------------------------------- prep
// Fused: xyz min-reduce (unsigned atomicMin on float bits; mn pre-set to
// 0xFFFFFFFF via hipMemsetAsync), table permute [idx][hd][c]->[c][idx][hd]
// (fp32), W transposes -> bf16 WT[outcol][k].
__global__ void prep_kernel(const float* __restrict__ xyz, int n,
                            const float* __restrict__ W_qkv,
                            const float* __restrict__ W_proj,
                            const float* __restrict__ tq, const float* __restrict__ tk,
                            const float* __restrict__ tv,
                            ushort* __restrict__ wtqkv, ushort* __restrict__ wtproj,
                            float* __restrict__ rq, float* __restrict__ rk,
                            float* __restrict__ rv, uint* __restrict__ mnbits) {
    int tid = blockIdx.x * 256 + threadIdx.x;
    if (tid < 18432) {  // tables: 3*64*96, keep fp32
        int c = tid / 6144, rem = tid - c * 6144;
        int idx = rem / 96, hd = rem - idx * 96;
        int src = (idx * 96 + hd) * 3 + c;
        rq[tid] = tq[src];
        rk[tid] = tk[src];
        rv[tid] = tv[src];
    }
    if (tid < 27648) {  // WT_qkv[j][d] = W_qkv[d][j], j over 288
        int j = tid / 96, d = tid - j * 96;
        wtqkv[tid] = f2bf(W_qkv[d * 288 + j]);
    }
    if (tid < 9216) {  // WT_proj[j][d] = W_proj[d][j]
        int j = tid / 96, d = tid - j * 96;
        wtproj[tid] = f2bf(W_proj[d * 96 + j]);
    }
    // min(xyz) — xyz >= 0 so float bits are monotone under unsigned compare
    float m0 = FLT_BIG, m1 = FLT_BIG, m2 = FLT_BIG;
    for (int i = tid; i < n; i += gridDim.x * 256) {
        m0 = fminf(m0, xyz[3 * i + 0]);
        m1 = fminf(m1, xyz[3 * i + 1]);
        m2 = fminf(m2, xyz[3 * i + 2]);
    }
#pragma unroll
    for (int off = 32; off > 0; off >>= 1) {
        m0 = fminf(m0, __shfl_down(m0, off));
        m1 = fminf(m1, __shfl_down(m1, off));
        m2 = fminf(m2, __shfl_down(m2, off));
    }
    if ((threadIdx.x & 63) == 0) {
        atomicMin(&mnbits[0], __float_as_uint(m0));
        atomicMin(&mnbits[1], __float_as_uint(m1));
        atomicMin(&mnbits[2], __float_as_uint(m2));
    }
}

// ---------------------------------------------------------------- QKV MFMA GEMM
// D = W·feats (operands swapped): A-frag = WT tile (A[m=colout][k=q*8+j]),
// B-frag = feats tile (B[k=q*8+j][n=point m]) — identical per-lane data to the
// unswapped A-frag. D[row=q*4+r][col=m] -> lane holds 4 CONSECUTIVE out cols of
// point m -> one packed ushort4 store per tile, no LDS epilogue.
// feats staged once per block in LDS (coalesced), fragments reused across all
// 3 channels x 6 col-tiles.
__global__ __launch_bounds__(256) void qkv_mfma_kernel(
    const float* __restrict__ feats, const ushort* __restrict__ WT,
    const float* __restrict__ bias, ushort* __restrict__ qout,
    ushort* __restrict__ kvout, int n) {
    __shared__ ushort As[128 * 104];  // pitch 104 ushort: 16B-aligned rows, 2-way max
    const int t = threadIdx.x;
    const int wave = t >> 6, lane = t & 63;
    const int m = lane & 15, q = lane >> 4;
    const int row0 = blockIdx.x * 128;

    const float4* F4 = (const float4*)feats;
    for (int i = t; i < 3072; i += 256) {
        int r = i / 24, c4 = i - r * 24;
        int gr = row0 + r;
        if (gr > n - 1) gr = n - 1;
        float4 f = F4[(size_t)gr * 24 + c4];
        ushort4 u;
        u.x = f2bf(f.x); u.y = f2bf(f.y); u.z = f2bf(f.z); u.w = f2bf(f.w);
        *(ushort4*)&As[r * 104 + c4 * 4] = u;
    }
    __syncthreads();

    short8 ff[2][3];
#pragma unroll
    for (int g = 0; g < 2; g++)
#pragma unroll
        for (int k = 0; k < 3; k++)
            ff[g][k] = *(const short8*)&As[(wave * 32 + g * 16 + m) * 104 + k * 32 + q * 8];

    const int p0 = row0 + wave * 32 + m;
    const int p1 = p0 + 16;

#pragma unroll
    for (int ch = 0; ch < 3; ch++) {
#pragma unroll
        for (int ct = 0; ct < 6; ct++) {
            floatx4 acc0 = (floatx4){0.f, 0.f, 0.f, 0.f};
            floatx4 acc1 = (floatx4){0.f, 0.f, 0.f, 0.f};
            const ushort* wb = WT + ((size_t)(ch * 96 + ct * 16 + m)) * 96 + q * 8;
#pragma unroll
            for (int k = 0; k < 3; k++) {
                short8 wf = *(const short8*)(wb + k * 32);
                acc0 = __builtin_amdgcn_mfma_f32_16x16x32_bf16(wf, ff[0][k], acc0, 0, 0, 0);
                acc1 = __builtin_amdgcn_mfma_f32_16x16x32_bf16(wf, ff[1][k], acc1, 0, 0, 0);
            }
            float4 bv = *(const float4*)&bias[ch * 96 + ct * 16 + q * 4];
            const float sc = (ch == 0) ? 0.25f : 1.0f;
#pragma unroll
            for (int g = 0; g < 2; g++) {
                int point = g ? p1 : p0;
                if (point < n) {
                    floatx4 a = g ? acc1 : acc0;
                    ushort4 u;
                    u.x = f2bf((a[0] + bv.x) * sc);
                    u.y = f2bf((a[1] + bv.y) * sc);
                    u.z = f2bf((a[2] + bv.z) * sc);
                    u.w = f2bf((a[3] + bv.w) * sc);
                    ushort* dst = (ch == 0)
                        ? qout + (size_t)point * 96 + ct * 16 + q * 4
                        : kvout + (size_t)point * 192 + ((ch == 2) ? 96 : 0) + ct * 16 + q * 4;
                    *(ushort4*)dst = u;
                }
            }
        }
    }
}

// ---------------------------------------------------------------- proj MFMA GEMM
// Same swapped-operand scheme; x is already bf16 so fragments load straight
// from global; out fp32 via one float4 store per tile per lane.
__global__ __launch_bounds__(256) void proj_mfma_kernel(
    const ushort* __restrict__ X, const ushort* __restrict__ WT,
    const float* __restrict__ bias, float* __restrict__ out, int n) {
    const int wave = threadIdx.x >> 6, lane = threadIdx.x & 63;
    const int m = lane & 15, q = lane >> 4;
    const int row0 = blockIdx.x * 128 + wave * 32;
    if (row0 >= n) return;
    int r0 = row0 + m;      if (r0 > n - 1) r0 = n - 1;
    int r1 = row0 + 16 + m; if (r1 > n - 1) r1 = n - 1;

    short8 xf[2][3];
#pragma unroll
    for (int k = 0; k < 3; k++) {
        xf[0][k] = *(const short8*)(X + (size_t)r0 * 96 + k * 32 + q * 8);
        xf[1][k] = *(const short8*)(X + (size_t)r1 * 96 + k * 32 + q * 8);
    }

#pragma unroll
    for (int ct = 0; ct < 6; ct++) {
        floatx4 acc0 = (floatx4){0.f, 0.f, 0.f, 0.f};
        floatx4 acc1 = (floatx4){0.f, 0.f, 0.f, 0.f};
        const ushort* wb = WT + ((size_t)(ct * 16 + m)) * 96 + q * 8;
#pragma unroll
        for (int k = 0; k < 3; k++) {
            short8 wf = *(const short8*)(wb + k * 32);
            acc0 = __builtin_amdgcn_mfma_f32_16x16x32_bf16(wf, xf[0][k], acc0, 0, 0, 0);
            acc1 = __builtin_amdgcn_mfma_f32_16x16x32_bf16(wf, xf[1][k], acc1, 0, 0, 0);
        }
        float4 bv = *(const float4*)&bias[ct * 16 + q * 4];
#pragma unroll
        for (int g = 0; g < 2; g++) {
            int point = row0 + g * 16 + m;
            if (point < n) {
                floatx4 a = g ? acc1 : acc0;
                float4 o;
                o.x = a[0] + bv.x; o.y = a[1] + bv.y;
                o.z = a[2] + bv.z; o.w = a[3] + bv.w;
                *(float4*)&out[(size_t)point * 96 + ct * 16 + q * 4] = o;
            }
        }
    }
}

// ---------------------------------------------------------------- fused attention
// q bf16, kv bf16 (k[96]||v[96] 384B rows), tables fp32 (no unpack VALU).
// vs pitch 108 floats: row starts span 8 banks -> <=2-way conflicts.
__global__ __launch_bounds__(192) void attn_kernel(
    const ushort* __restrict__ qbf, const ushort* __restrict__ kv,
    const float* __restrict__ xyz, const int* __restrict__ index_1,
    const float* __restrict__ rq, const float* __restrict__ rk,
    const float* __restrict__ rv, const float* __restrict__ mn,
    const float* __restrict__ shiftp, ushort* xout, int n) {
    __shared__ float qs[2][96];
    __shared__ float vs[2][16][108];
    __shared__ float smw[2][6][16];
    __shared__ int ridx[2][16][3];

    const int s = threadIdx.x / 96;
    const int tp = threadIdx.x - s * 96;
    const int p = blockIdx.x * 2 + s;
    const bool active = p < n;
    const float shift = shiftp[0];

    const int h = tp >> 4;  // 0..5
    const int e = tp & 15;

    int jd = 0;
    if (active) jd = index_1[(size_t)p * 16 + e];

    // ---- rel quantized index (48 thr/point) + q row unpack (48 thr/point)
    if (active && tp < 48) {
        const int c = tp >> 4;
        const float mnc = mn[c];
        float xi = floorf(fmodf(xyz[3 * p + c] - mnc + shift, 4.0f) * 4.0f);
        float xj = floorf(fmodf(xyz[3 * jd + c] - mnc + shift, 4.0f) * 4.0f);
        ridx[s][e][c] = (int)(xi - xj) + 15;
        uint qu = *(const uint*)(qbf + (size_t)p * 96 + tp * 2);
        qs[s][tp * 2] = bl(qu);
        qs[s][tp * 2 + 1] = bh(qu);
    }

    // ---- gather: k fragment into regs, v fragment into LDS
    float4 k0, k1, k2, k3;
    k0 = k1 = k2 = k3 = make_float4(0.f, 0.f, 0.f, 0.f);
    if (active) {
        const ushort* row = kv + (size_t)jd * 192;
        uint4 ka = *(const uint4*)(row + h * 16);
        uint4 kb = *(const uint4*)(row + h * 16 + 8);
        uint4 va = *(const uint4*)(row + 96 + h * 16);
        uint4 vb = *(const uint4*)(row + 96 + h * 16 + 8);
        k0 = make_float4(bl(ka.x), bh(ka.x), bl(ka.y), bh(ka.y));
        k1 = make_float4(bl(ka.z), bh(ka.z), bl(ka.w), bh(ka.w));
        k2 = make_float4(bl(kb.x), bh(kb.x), bl(kb.y), bh(kb.y));
        k3 = make_float4(bl(kb.z), bh(kb.z), bl(kb.w), bh(kb.w));
        *(float4*)&vs[s][e][h * 16 + 0]  = make_float4(bl(va.x), bh(va.x), bl(va.y), bh(va.y));
        *(float4*)&vs[s][e][h * 16 + 4]  = make_float4(bl(va.z), bh(va.z), bl(va.w), bh(va.w));
        *(float4*)&vs[s][e][h * 16 + 8]  = make_float4(bl(vb.x), bh(vb.x), bl(vb.y), bh(vb.y));
        *(float4*)&vs[s][e][h * 16 + 12] = make_float4(bl(vb.z), bh(vb.z), bl(vb.w), bh(vb.w));
    }
    __syncthreads();

    // ---- fold table-v bias into vs: 192 tasks; e2 = t2&15 so a 16-lane group
    // sweeps 16 distinct rows (bank-friendly with pitch 108)
    if (active) {
#pragma unroll
        for (int it = 0; it < 2; it++) {
            int t2 = tp + 96 * it;
            int e2 = t2 & 15, c8 = t2 >> 4;  // c8 in 0..11
            int i0 = ridx[s][e2][0], i1 = ridx[s][e2][1], i2 = ridx[s][e2][2];
            const float4* p0 = (const float4*)(rv + i0 * 96 + c8 * 8);
            const float4* p1 = (const float4*)(rv + (64 + i1) * 96 + c8 * 8);
            const float4* p2 = (const float4*)(rv + (128 + i2) * 96 + c8 * 8);
            float4 u00 = p0[0], u01 = p0[1];
            float4 u10 = p1[0], u11 = p1[1];
            float4 u20 = p2[0], u21 = p2[1];
            float4* vp = (float4*)&vs[s][e2][c8 * 8];
            float4 a0 = vp[0], a1 = vp[1];
            a0.x += u00.x + u10.x + u20.x;
            a0.y += u00.y + u10.y + u20.y;
            a0.z += u00.z + u10.z + u20.z;
            a0.w += u00.w + u10.w + u20.w;
            a1.x += u01.x + u11.x + u21.x;
            a1.y += u01.y + u11.y + u21.y;
            a1.z += u01.z + u11.z + u21.z;
            a1.w += u01.w + u11.w + u21.w;
            vp[0] = a0; vp[1] = a1;
        }
    }

    // ---- score: qk + fp32 bias tables, then width-16 shuffle softmax
    {
        const float4* q4 = (const float4*)&qs[s][h * 16];
        float4 qa = q4[0], qb = q4[1], qc = q4[2], qd = q4[3];
        float a = dot4(qa, k0) + dot4(qb, k1) + dot4(qc, k2) + dot4(qd, k3);
#pragma unroll
        for (int c = 0; c < 3; c++) {
            int idx = ridx[s][e][c];
            const float4* tq4 = (const float4*)(rq + (c * 64 + idx) * 96 + h * 16);
            const float4* tk4 = (const float4*)(rk + (c * 64 + idx) * 96 + h * 16);
            a += dot4(qa, tq4[0]) + dot4(qb, tq4[1]) + dot4(qc, tq4[2]) + dot4(qd, tq4[3]);
            a += dot4(k0, tk4[0]) + dot4(k1, tk4[1]) + dot4(k2, tk4[2]) + dot4(k3, tk4[3]);
        }
        float m = a;
#pragma unroll
        for (int off = 8; off >= 1; off >>= 1) m = fmaxf(m, __shfl_xor(m, off, 16));
        float ex = __expf(a - m);
        float sum = ex;
#pragma unroll
        for (int off = 8; off >= 1; off >>= 1) sum += __shfl_xor(sum, off, 16);
        if (active) smw[s][h][e] = ex / sum;
    }
    __syncthreads();

    // ---- output: pure LDS-FMA, emit bf16 x
    {
        float x = 0.f;
#pragma unroll
        for (int ee = 0; ee < 16; ee++) x += smw[s][h][ee] * vs[s][ee][tp];
        if (active) xout[(size_t)p * 96 + tp] = f2bf(x);
    }
}

// ---------------------------------------------------------------- launch
extern "C" void kernel_launch(void* const* d_in, const int* in_sizes, int n_in,
                              void* d_out, int out_size, void* d_ws, size_t ws_size,
                              hipStream_t stream) {
    const float* feats   = (const float*)d_in[0];
    const float* xyz     = (const float*)d_in[1];
    const int*   index_1 = (const int*)d_in[5];
    const float* shiftp  = (const float*)d_in[6];
    const float* W_qkv   = (const float*)d_in[7];
    const float* b_qkv   = (const float*)d_in[8];
    const float* table_q = (const float*)d_in[9];
    const float* table_k = (const float*)d_in[10];
    const float* table_v = (const float*)d_in[11];
    const float* W_proj  = (const float*)d_in[12];
    const float* b_proj  = (const float*)d_in[13];
    float* out = (float*)d_out;

    const int n = in_sizes[0] / 96;  // 50000

    float* w = (float*)d_ws;
    float*  mn     = w;                         // 16 floats (uint-min bits)
    ushort* qbf    = (ushort*)(w + 16);         // n*96 bf16
    ushort* kvbuf  = qbf + (size_t)n * 96;      // n*192 bf16
    ushort* xbuf   = kvbuf + (size_t)n * 192;   // n*96 bf16
    ushort* wtqkv  = xbuf + (size_t)n * 96;     // 27648 bf16
    ushort* wtproj = wtqkv + 27648;             // 9216 bf16
    float*  rq     = (float*)(wtproj + 9216);   // 18432 fp32 each
    float*  rk     = rq + 18432;
    float*  rv     = rk + 18432;

    const int GB = (n + 127) / 128;

    hipMemsetAsync(mn, 0xFF, 16 * sizeof(float), stream);  // +inf for unsigned min
    prep_kernel<<<256, 256, 0, stream>>>(xyz, n, W_qkv, W_proj, table_q, table_k,
                                         table_v, wtqkv, wtproj, rq, rk, rv,
                                         (uint*)mn);
    qkv_mfma_kernel<<<GB, 256, 0, stream>>>(feats, wtqkv, b_qkv, qbf, kvbuf, n);
    attn_kernel<<<(n + 1) / 2, 192, 0, stream>>>(qbf, kvbuf, xyz, index_1, rq, rk,
                                                 rv, mn, shiftp, xbuf, n);
    proj_mfma_kernel<<<GB, 256, 0, stream>>>(xbuf, wtproj, b_proj, out, n);
}

// Round 8
// 328.107 us; speedup vs baseline: 1.4218x; 1.4218x over previous
//
#include <hip/hip_runtime.h>
#include <math.h>

#define FLT_BIG 3.402823466e38f
typedef unsigned int uint;
typedef unsigned short ushort;
typedef __attribute__((ext_vector_type(8))) short short8;   // 8 bf16 (4 VGPRs)
typedef __attribute__((ext_vector_type(4))) float floatx4;  // MFMA C/D frag

__device__ inline float bl(uint u) { return __uint_as_float(u << 16); }
__device__ inline float bh(uint u) { return __uint_as_float(u & 0xffff0000u); }
__device__ inline ushort f2bf(float f) {  // RNE
    uint u = __float_as_uint(f);
    return (ushort)((u + 0x7fffu + ((u >> 16) & 1u)) >> 16);
}
__device__ inline float dot4(float4 a, float4 b) {
    return a.x * b.x + a.y * b.y + a.z * b.z + a.w * b.w;
}

// ---------------------------------------------------------------- prep
// Fused: xyz min-reduce (unsigned atomicMin on float bits; mn pre-set to
// 0xFFFFFFFF via hipMemsetAsync), table permute [idx][hd][c]->[c][idx][hd]
// bf16, W transposes -> bf16 WT[outcol][k].
__global__ void prep_kernel(const float* __restrict__ xyz, int n,
                            const float* __restrict__ W_qkv,
                            const float* __restrict__ W_proj,
                            const float* __restrict__ tq, const float* __restrict__ tk,
                            const float* __restrict__ tv,
                            ushort* __restrict__ wtqkv, ushort* __restrict__ wtproj,
                            ushort* __restrict__ rq, ushort* __restrict__ rk,
                            ushort* __restrict__ rv, uint* __restrict__ mnbits) {
    int tid = blockIdx.x * 256 + threadIdx.x;
    if (tid < 18432) {  // tables: 3*64*96 -> bf16 (R6-proven precision)
        int c = tid / 6144, rem = tid - c * 6144;
        int idx = rem / 96, hd = rem - idx * 96;
        int src = (idx * 96 + hd) * 3 + c;
        rq[tid] = f2bf(tq[src]);
        rk[tid] = f2bf(tk[src]);
        rv[tid] = f2bf(tv[src]);
    }
    if (tid < 27648) {  // WT_qkv[j][d] = W_qkv[d][j], j over 288
        int j = tid / 96, d = tid - j * 96;
        wtqkv[tid] = f2bf(W_qkv[d * 288 + j]);
    }
    if (tid < 9216) {  // WT_proj[j][d] = W_proj[d][j]
        int j = tid / 96, d = tid - j * 96;
        wtproj[tid] = f2bf(W_proj[d * 96 + j]);
    }
    // min(xyz) — xyz >= 0 so float bits are monotone under unsigned compare
    float m0 = FLT_BIG, m1 = FLT_BIG, m2 = FLT_BIG;
    for (int i = tid; i < n; i += gridDim.x * 256) {
        m0 = fminf(m0, xyz[3 * i + 0]);
        m1 = fminf(m1, xyz[3 * i + 1]);
        m2 = fminf(m2, xyz[3 * i + 2]);
    }
#pragma unroll
    for (int off = 32; off > 0; off >>= 1) {
        m0 = fminf(m0, __shfl_down(m0, off));
        m1 = fminf(m1, __shfl_down(m1, off));
        m2 = fminf(m2, __shfl_down(m2, off));
    }
    if ((threadIdx.x & 63) == 0) {
        atomicMin(&mnbits[0], __float_as_uint(m0));
        atomicMin(&mnbits[1], __float_as_uint(m1));
        atomicMin(&mnbits[2], __float_as_uint(m2));
    }
}

// ---------------------------------------------------------------- QKV MFMA GEMM
// D = W·feats (swapped operands): D[row=q*4+r][col=m] -> lane holds 4
// consecutive out cols of point m -> packed ushort4 stores, no LDS epilogue.
__global__ __launch_bounds__(256) void qkv_mfma_kernel(
    const float* __restrict__ feats, const ushort* __restrict__ WT,
    const float* __restrict__ bias, ushort* __restrict__ qout,
    ushort* __restrict__ kvout, int n) {
    __shared__ ushort As[128 * 104];  // pitch 104 ushort
    const int t = threadIdx.x;
    const int wave = t >> 6, lane = t & 63;
    const int m = lane & 15, q = lane >> 4;
    const int row0 = blockIdx.x * 128;

    const float4* F4 = (const float4*)feats;
    for (int i = t; i < 3072; i += 256) {
        int r = i / 24, c4 = i - r * 24;
        int gr = row0 + r;
        if (gr > n - 1) gr = n - 1;
        float4 f = F4[(size_t)gr * 24 + c4];
        ushort4 u;
        u.x = f2bf(f.x); u.y = f2bf(f.y); u.z = f2bf(f.z); u.w = f2bf(f.w);
        *(ushort4*)&As[r * 104 + c4 * 4] = u;
    }
    __syncthreads();

    short8 ff[2][3];
#pragma unroll
    for (int g = 0; g < 2; g++)
#pragma unroll
        for (int k = 0; k < 3; k++)
            ff[g][k] = *(const short8*)&As[(wave * 32 + g * 16 + m) * 104 + k * 32 + q * 8];

    const int p0 = row0 + wave * 32 + m;
    const int p1 = p0 + 16;

#pragma unroll
    for (int ch = 0; ch < 3; ch++) {
#pragma unroll
        for (int ct = 0; ct < 6; ct++) {
            floatx4 acc0 = (floatx4){0.f, 0.f, 0.f, 0.f};
            floatx4 acc1 = (floatx4){0.f, 0.f, 0.f, 0.f};
            const ushort* wb = WT + ((size_t)(ch * 96 + ct * 16 + m)) * 96 + q * 8;
#pragma unroll
            for (int k = 0; k < 3; k++) {
                short8 wf = *(const short8*)(wb + k * 32);
                acc0 = __builtin_amdgcn_mfma_f32_16x16x32_bf16(wf, ff[0][k], acc0, 0, 0, 0);
                acc1 = __builtin_amdgcn_mfma_f32_16x16x32_bf16(wf, ff[1][k], acc1, 0, 0, 0);
            }
            float4 bv = *(const float4*)&bias[ch * 96 + ct * 16 + q * 4];
            const float sc = (ch == 0) ? 0.25f : 1.0f;
#pragma unroll
            for (int g = 0; g < 2; g++) {
                int point = g ? p1 : p0;
                if (point < n) {
                    floatx4 a = g ? acc1 : acc0;
                    ushort4 u;
                    u.x = f2bf((a[0] + bv.x) * sc);
                    u.y = f2bf((a[1] + bv.y) * sc);
                    u.z = f2bf((a[2] + bv.z) * sc);
                    u.w = f2bf((a[3] + bv.w) * sc);
                    ushort* dst = (ch == 0)
                        ? qout + (size_t)point * 96 + ct * 16 + q * 4
                        : kvout + (size_t)point * 192 + ((ch == 2) ? 96 : 0) + ct * 16 + q * 4;
                    *(ushort4*)dst = u;
                }
            }
        }
    }
}

// ---------------------------------------------------------------- proj MFMA GEMM
__global__ __launch_bounds__(256) void proj_mfma_kernel(
    const ushort* __restrict__ X, const ushort* __restrict__ WT,
    const float* __restrict__ bias, float* __restrict__ out, int n) {
    const int wave = threadIdx.x >> 6, lane = threadIdx.x & 63;
    const int m = lane & 15, q = lane >> 4;
    const int row0 = blockIdx.x * 128 + wave * 32;
    if (row0 >= n) return;
    int r0 = row0 + m;      if (r0 > n - 1) r0 = n - 1;
    int r1 = row0 + 16 + m; if (r1 > n - 1) r1 = n - 1;

    short8 xf[2][3];
#pragma unroll
    for (int k = 0; k < 3; k++) {
        xf[0][k] = *(const short8*)(X + (size_t)r0 * 96 + k * 32 + q * 8);
        xf[1][k] = *(const short8*)(X + (size_t)r1 * 96 + k * 32 + q * 8);
    }

#pragma unroll
    for (int ct = 0; ct < 6; ct++) {
        floatx4 acc0 = (floatx4){0.f, 0.f, 0.f, 0.f};
        floatx4 acc1 = (floatx4){0.f, 0.f, 0.f, 0.f};
        const ushort* wb = WT + ((size_t)(ct * 16 + m)) * 96 + q * 8;
#pragma unroll
        for (int k = 0; k < 3; k++) {
            short8 wf = *(const short8*)(wb + k * 32);
            acc0 = __builtin_amdgcn_mfma_f32_16x16x32_bf16(wf, xf[0][k], acc0, 0, 0, 0);
            acc1 = __builtin_amdgcn_mfma_f32_16x16x32_bf16(wf, xf[1][k], acc1, 0, 0, 0);
        }
        float4 bv = *(const float4*)&bias[ct * 16 + q * 4];
#pragma unroll
        for (int g = 0; g < 2; g++) {
            int point = row0 + g * 16 + m;
            if (point < n) {
                floatx4 a = g ? acc1 : acc0;
                float4 o;
                o.x = a[0] + bv.x; o.y = a[1] + bv.y;
                o.z = a[2] + bv.z; o.w = a[3] + bv.w;
                *(float4*)&out[(size_t)point * 96 + ct * 16 + q * 4] = o;
            }
        }
    }
}

// ---------------------------------------------------------------- fused attention
// R6 dataflow (bf16 tables, per-c batched uint4 loads) + 4 points/block
// (384 thr, ~29.4KB LDS -> 5 blocks/CU = 94% occupancy) + conflict fixes
// (vs pitch 100: row-start float4 offset 25e mod 8 sweeps all 8; fold remap).
__global__ __launch_bounds__(384) void attn_kernel(
    const ushort* __restrict__ qbf, const ushort* __restrict__ kv,
    const float* __restrict__ xyz, const int* __restrict__ index_1,
    const ushort* __restrict__ rq, const ushort* __restrict__ rk,
    const ushort* __restrict__ rv, const float* __restrict__ mn,
    const float* __restrict__ shiftp, ushort* xout, int n) {
    __shared__ float qs[4][96];
    __shared__ float vs[4][16][100];
    __shared__ float smw[4][6][16];
    __shared__ int ridx[4][16][3];

    const int s = threadIdx.x / 96;
    const int tp = threadIdx.x - s * 96;
    const int p = blockIdx.x * 4 + s;
    const bool active = p < n;
    const float shift = shiftp[0];

    const int h = tp >> 4;  // 0..5
    const int e = tp & 15;

    int jd = 0;
    if (active) jd = index_1[(size_t)p * 16 + e];

    // ---- rel quantized index (48 thr/point) + q row unpack (48 thr/point)
    if (active && tp < 48) {
        const int c = tp >> 4;
        const float mnc = mn[c];
        float xi = floorf(fmodf(xyz[3 * p + c] - mnc + shift, 4.0f) * 4.0f);
        float xj = floorf(fmodf(xyz[3 * jd + c] - mnc + shift, 4.0f) * 4.0f);
        ridx[s][e][c] = (int)(xi - xj) + 15;
        uint qu = *(const uint*)(qbf + (size_t)p * 96 + tp * 2);
        qs[s][tp * 2] = bl(qu);
        qs[s][tp * 2 + 1] = bh(qu);
    }

    // ---- gather: k fragment into regs, v fragment into LDS
    float4 k0, k1, k2, k3;
    k0 = k1 = k2 = k3 = make_float4(0.f, 0.f, 0.f, 0.f);
    if (active) {
        const ushort* row = kv + (size_t)jd * 192;
        uint4 ka = *(const uint4*)(row + h * 16);
        uint4 kb = *(const uint4*)(row + h * 16 + 8);
        uint4 va = *(const uint4*)(row + 96 + h * 16);
        uint4 vb = *(const uint4*)(row + 96 + h * 16 + 8);
        k0 = make_float4(bl(ka.x), bh(ka.x), bl(ka.y), bh(ka.y));
        k1 = make_float4(bl(ka.z), bh(ka.z), bl(ka.w), bh(ka.w));
        k2 = make_float4(bl(kb.x), bh(kb.x), bl(kb.y), bh(kb.y));
        k3 = make_float4(bl(kb.z), bh(kb.z), bl(kb.w), bh(kb.w));
        *(float4*)&vs[s][e][h * 16 + 0]  = make_float4(bl(va.x), bh(va.x), bl(va.y), bh(va.y));
        *(float4*)&vs[s][e][h * 16 + 4]  = make_float4(bl(va.z), bh(va.z), bl(va.w), bh(va.w));
        *(float4*)&vs[s][e][h * 16 + 8]  = make_float4(bl(vb.x), bh(vb.x), bl(vb.y), bh(vb.y));
        *(float4*)&vs[s][e][h * 16 + 12] = make_float4(bl(vb.z), bh(vb.z), bl(vb.w), bh(vb.w));
    }
    __syncthreads();

    // ---- fold table-v bias into vs: e2 = t2&15 so a 16-lane group sweeps 16
    // distinct rows (pitch 100 -> row starts span all 8 float4 offsets)
    if (active) {
#pragma unroll
        for (int it = 0; it < 2; it++) {
            int t2 = tp + 96 * it;
            int e2 = t2 & 15, c8 = t2 >> 4;  // c8 in 0..11
            int i0 = ridx[s][e2][0], i1 = ridx[s][e2][1], i2 = ridx[s][e2][2];
            uint4 u0 = *(const uint4*)(rv + i0 * 96 + c8 * 8);
            uint4 u1 = *(const uint4*)(rv + (64 + i1) * 96 + c8 * 8);
            uint4 u2 = *(const uint4*)(rv + (128 + i2) * 96 + c8 * 8);
            float4* vp = (float4*)&vs[s][e2][c8 * 8];
            float4 a0 = vp[0], a1 = vp[1];
            a0.x += bl(u0.x) + bl(u1.x) + bl(u2.x);
            a0.y += bh(u0.x) + bh(u1.x) + bh(u2.x);
            a0.z += bl(u0.y) + bl(u1.y) + bl(u2.y);
            a0.w += bh(u0.y) + bh(u1.y) + bh(u2.y);
            a1.x += bl(u0.z) + bl(u1.z) + bl(u2.z);
            a1.y += bh(u0.z) + bh(u1.z) + bh(u2.z);
            a1.z += bl(u0.w) + bl(u1.w) + bl(u2.w);
            a1.w += bh(u0.w) + bh(u1.w) + bh(u2.w);
            vp[0] = a0; vp[1] = a1;
        }
    }

    // ---- score: qk + bf16 bias tables (per-c batched loads), shuffle softmax
    {
        const float4* q4 = (const float4*)&qs[s][h * 16];
        float4 qa = q4[0], qb = q4[1], qc = q4[2], qd = q4[3];
        float a = dot4(qa, k0) + dot4(qb, k1) + dot4(qc, k2) + dot4(qd, k3);
#pragma unroll
        for (int c = 0; c < 3; c++) {
            int idx = ridx[s][e][c];
            const uint4* tq4 = (const uint4*)(rq + (c * 64 + idx) * 96 + h * 16);
            const uint4* tk4 = (const uint4*)(rk + (c * 64 + idx) * 96 + h * 16);
            uint4 t0 = tq4[0], t1 = tq4[1];
            a += qa.x * bl(t0.x) + qa.y * bh(t0.x) + qa.z * bl(t0.y) + qa.w * bh(t0.y) +
                 qb.x * bl(t0.z) + qb.y * bh(t0.z) + qb.z * bl(t0.w) + qb.w * bh(t0.w) +
                 qc.x * bl(t1.x) + qc.y * bh(t1.x) + qc.z * bl(t1.y) + qc.w * bh(t1.y) +
                 qd.x * bl(t1.z) + qd.y * bh(t1.z) + qd.z * bl(t1.w) + qd.w * bh(t1.w);
            uint4 u0 = tk4[0], u1 = tk4[1];
            a += k0.x * bl(u0.x) + k0.y * bh(u0.x) + k0.z * bl(u0.y) + k0.w * bh(u0.y) +
                 k1.x * bl(u0.z) + k1.y * bh(u0.z) + k1.z * bl(u0.w) + k1.w * bh(u0.w) +
                 k2.x * bl(u1.x) + k2.y * bh(u1.x) + k2.z * bl(u1.y) + k2.w * bh(u1.y) +
                 k3.x * bl(u1.z) + k3.y * bh(u1.z) + k3.z * bl(u1.w) + k3.w * bh(u1.w);
        }
        float m = a;
#pragma unroll
        for (int off = 8; off >= 1; off >>= 1) m = fmaxf(m, __shfl_xor(m, off, 16));
        float ex = __expf(a - m);
        float sum = ex;
#pragma unroll
        for (int off = 8; off >= 1; off >>= 1) sum += __shfl_xor(sum, off, 16);
        if (active) smw[s][h][e] = ex / sum;
    }
    __syncthreads();

    // ---- output: pure LDS-FMA, emit bf16 x
    {
        float x = 0.f;
#pragma unroll
        for (int ee = 0; ee < 16; ee++) x += smw[s][h][ee] * vs[s][ee][tp];
        if (active) xout[(size_t)p * 96 + tp] = f2bf(x);
    }
}

// ---------------------------------------------------------------- launch
extern "C" void kernel_launch(void* const* d_in, const int* in_sizes, int n_in,
                              void* d_out, int out_size, void* d_ws, size_t ws_size,
                              hipStream_t stream) {
    const float* feats   = (const float*)d_in[0];
    const float* xyz     = (const float*)d_in[1];
    const int*   index_1 = (const int*)d_in[5];
    const float* shiftp  = (const float*)d_in[6];
    const float* W_qkv   = (const float*)d_in[7];
    const float* b_qkv   = (const float*)d_in[8];
    const float* table_q = (const float*)d_in[9];
    const float* table_k = (const float*)d_in[10];
    const float* table_v = (const float*)d_in[11];
    const float* W_proj  = (const float*)d_in[12];
    const float* b_proj  = (const float*)d_in[13];
    float* out = (float*)d_out;

    const int n = in_sizes[0] / 96;  // 50000

    float* w = (float*)d_ws;
    float*  mn     = w;                         // 16 floats (uint-min bits)
    ushort* qbf    = (ushort*)(w + 16);         // n*96 bf16
    ushort* kvbuf  = qbf + (size_t)n * 96;      // n*192 bf16
    ushort* xbuf   = kvbuf + (size_t)n * 192;   // n*96 bf16
    ushort* wtqkv  = xbuf + (size_t)n * 96;     // 27648 bf16
    ushort* wtproj = wtqkv + 27648;             // 9216 bf16
    ushort* rq     = wtproj + 9216;             // 18432 bf16 each
    ushort* rk     = rq + 18432;
    ushort* rv     = rk + 18432;

    const int GB = (n + 127) / 128;

    hipMemsetAsync(mn, 0xFF, 16 * sizeof(float), stream);  // +inf for unsigned min
    prep_kernel<<<256, 256, 0, stream>>>(xyz, n, W_qkv, W_proj, table_q, table_k,
                                         table_v, wtqkv, wtproj, rq, rk, rv,
                                         (uint*)mn);
    qkv_mfma_kernel<<<GB, 256, 0, stream>>>(feats, wtqkv, b_qkv, qbf, kvbuf, n);
    attn_kernel<<<(n + 3) / 4, 384, 0, stream>>>(qbf, kvbuf, xyz, index_1, rq, rk,
                                                 rv, mn, shiftp, xbuf, n);
    proj_mfma_kernel<<<GB, 256, 0, stream>>>(xbuf, wtproj, b_proj, out, n);
}

// Round 9
// 298.232 us; speedup vs baseline: 1.5642x; 1.1002x over previous
//
#include <hip/hip_runtime.h>
#include <math.h>

#define FLT_BIG 3.402823466e38f
typedef unsigned int uint;
typedef unsigned short ushort;
typedef __attribute__((ext_vector_type(8))) short short8;   // 8 bf16 (4 VGPRs)
typedef __attribute__((ext_vector_type(4))) float floatx4;  // MFMA C/D frag

__device__ inline float bl(uint u) { return __uint_as_float(u << 16); }
__device__ inline float bh(uint u) { return __uint_as_float(u & 0xffff0000u); }
__device__ inline ushort f2bf(float f) {  // RNE
    uint u = __float_as_uint(f);
    return (ushort)((u + 0x7fffu + ((u >> 16) & 1u)) >> 16);
}
__device__ inline float dot4(float4 a, float4 b) {
    return a.x * b.x + a.y * b.y + a.z * b.z + a.w * b.w;
}

// ---------------------------------------------------------------- prep
// Fused: xyz min-reduce (unsigned atomicMin on float bits; mn pre-set to
// 0xFFFFFFFF via hipMemsetAsync), table permute [idx][hd][c]->[c][idx][hd]
// bf16, W transposes -> bf16 WT[outcol][k].
__global__ void prep_kernel(const float* __restrict__ xyz, int n,
                            const float* __restrict__ W_qkv,
                            const float* __restrict__ W_proj,
                            const float* __restrict__ tq, const float* __restrict__ tk,
                            const float* __restrict__ tv,
                            ushort* __restrict__ wtqkv, ushort* __restrict__ wtproj,
                            ushort* __restrict__ rq, ushort* __restrict__ rk,
                            ushort* __restrict__ rv, uint* __restrict__ mnbits) {
    int tid = blockIdx.x * 256 + threadIdx.x;
    if (tid < 18432) {  // tables: 3*64*96 -> bf16
        int c = tid / 6144, rem = tid - c * 6144;
        int idx = rem / 96, hd = rem - idx * 96;
        int src = (idx * 96 + hd) * 3 + c;
        rq[tid] = f2bf(tq[src]);
        rk[tid] = f2bf(tk[src]);
        rv[tid] = f2bf(tv[src]);
    }
    if (tid < 27648) {  // WT_qkv[j][d] = W_qkv[d][j], j over 288
        int j = tid / 96, d = tid - j * 96;
        wtqkv[tid] = f2bf(W_qkv[d * 288 + j]);
    }
    if (tid < 9216) {  // WT_proj[j][d] = W_proj[d][j]
        int j = tid / 96, d = tid - j * 96;
        wtproj[tid] = f2bf(W_proj[d * 96 + j]);
    }
    // min(xyz) — xyz >= 0 so float bits are monotone under unsigned compare
    float m0 = FLT_BIG, m1 = FLT_BIG, m2 = FLT_BIG;
    for (int i = tid; i < n; i += gridDim.x * 256) {
        m0 = fminf(m0, xyz[3 * i + 0]);
        m1 = fminf(m1, xyz[3 * i + 1]);
        m2 = fminf(m2, xyz[3 * i + 2]);
    }
#pragma unroll
    for (int off = 32; off > 0; off >>= 1) {
        m0 = fminf(m0, __shfl_down(m0, off));
        m1 = fminf(m1, __shfl_down(m1, off));
        m2 = fminf(m2, __shfl_down(m2, off));
    }
    if ((threadIdx.x & 63) == 0) {
        atomicMin(&mnbits[0], __float_as_uint(m0));
        atomicMin(&mnbits[1], __float_as_uint(m1));
        atomicMin(&mnbits[2], __float_as_uint(m2));
    }
}

// ---------------------------------------------------------------- QKV MFMA GEMM
// D = W·feats (swapped operands): D[row=q*4+r][col=m] -> lane holds 4
// consecutive out cols of point m -> packed ushort4 stores, no LDS epilogue.
__global__ __launch_bounds__(256) void qkv_mfma_kernel(
    const float* __restrict__ feats, const ushort* __restrict__ WT,
    const float* __restrict__ bias, ushort* __restrict__ qout,
    ushort* __restrict__ kvout, int n) {
    __shared__ ushort As[128 * 104];  // pitch 104 ushort
    const int t = threadIdx.x;
    const int wave = t >> 6, lane = t & 63;
    const int m = lane & 15, q = lane >> 4;
    const int row0 = blockIdx.x * 128;

    const float4* F4 = (const float4*)feats;
    for (int i = t; i < 3072; i += 256) {
        int r = i / 24, c4 = i - r * 24;
        int gr = row0 + r;
        if (gr > n - 1) gr = n - 1;
        float4 f = F4[(size_t)gr * 24 + c4];
        ushort4 u;
        u.x = f2bf(f.x); u.y = f2bf(f.y); u.z = f2bf(f.z); u.w = f2bf(f.w);
        *(ushort4*)&As[r * 104 + c4 * 4] = u;
    }
    __syncthreads();

    short8 ff[2][3];
#pragma unroll
    for (int g = 0; g < 2; g++)
#pragma unroll
        for (int k = 0; k < 3; k++)
            ff[g][k] = *(const short8*)&As[(wave * 32 + g * 16 + m) * 104 + k * 32 + q * 8];

    const int p0 = row0 + wave * 32 + m;
    const int p1 = p0 + 16;

#pragma unroll
    for (int ch = 0; ch < 3; ch++) {
#pragma unroll
        for (int ct = 0; ct < 6; ct++) {
            floatx4 acc0 = (floatx4){0.f, 0.f, 0.f, 0.f};
            floatx4 acc1 = (floatx4){0.f, 0.f, 0.f, 0.f};
            const ushort* wb = WT + ((size_t)(ch * 96 + ct * 16 + m)) * 96 + q * 8;
#pragma unroll
            for (int k = 0; k < 3; k++) {
                short8 wf = *(const short8*)(wb + k * 32);
                acc0 = __builtin_amdgcn_mfma_f32_16x16x32_bf16(wf, ff[0][k], acc0, 0, 0, 0);
                acc1 = __builtin_amdgcn_mfma_f32_16x16x32_bf16(wf, ff[1][k], acc1, 0, 0, 0);
            }
            float4 bv = *(const float4*)&bias[ch * 96 + ct * 16 + q * 4];
            const float sc = (ch == 0) ? 0.25f : 1.0f;
#pragma unroll
            for (int g = 0; g < 2; g++) {
                int point = g ? p1 : p0;
                if (point < n) {
                    floatx4 a = g ? acc1 : acc0;
                    ushort4 u;
                    u.x = f2bf((a[0] + bv.x) * sc);
                    u.y = f2bf((a[1] + bv.y) * sc);
                    u.z = f2bf((a[2] + bv.z) * sc);
                    u.w = f2bf((a[3] + bv.w) * sc);
                    ushort* dst = (ch == 0)
                        ? qout + (size_t)point * 96 + ct * 16 + q * 4
                        : kvout + (size_t)point * 192 + ((ch == 2) ? 96 : 0) + ct * 16 + q * 4;
                    *(ushort4*)dst = u;
                }
            }
        }
    }
}

// ---------------------------------------------------------------- proj MFMA GEMM
__global__ __launch_bounds__(256) void proj_mfma_kernel(
    const ushort* __restrict__ X, const ushort* __restrict__ WT,
    const float* __restrict__ bias, float* __restrict__ out, int n) {
    const int wave = threadIdx.x >> 6, lane = threadIdx.x & 63;
    const int m = lane & 15, q = lane >> 4;
    const int row0 = blockIdx.x * 128 + wave * 32;
    if (row0 >= n) return;
    int r0 = row0 + m;      if (r0 > n - 1) r0 = n - 1;
    int r1 = row0 + 16 + m; if (r1 > n - 1) r1 = n - 1;

    short8 xf[2][3];
#pragma unroll
    for (int k = 0; k < 3; k++) {
        xf[0][k] = *(const short8*)(X + (size_t)r0 * 96 + k * 32 + q * 8);
        xf[1][k] = *(const short8*)(X + (size_t)r1 * 96 + k * 32 + q * 8);
    }

#pragma unroll
    for (int ct = 0; ct < 6; ct++) {
        floatx4 acc0 = (floatx4){0.f, 0.f, 0.f, 0.f};
        floatx4 acc1 = (floatx4){0.f, 0.f, 0.f, 0.f};
        const ushort* wb = WT + ((size_t)(ct * 16 + m)) * 96 + q * 8;
#pragma unroll
        for (int k = 0; k < 3; k++) {
            short8 wf = *(const short8*)(wb + k * 32);
            acc0 = __builtin_amdgcn_mfma_f32_16x16x32_bf16(wf, xf[0][k], acc0, 0, 0, 0);
            acc1 = __builtin_amdgcn_mfma_f32_16x16x32_bf16(wf, xf[1][k], acc1, 0, 0, 0);
        }
        float4 bv = *(const float4*)&bias[ct * 16 + q * 4];
#pragma unroll
        for (int g = 0; g < 2; g++) {
            int point = row0 + g * 16 + m;
            if (point < n) {
                floatx4 a = g ? acc1 : acc0;
                float4 o;
                o.x = a[0] + bv.x; o.y = a[1] + bv.y;
                o.z = a[2] + bv.z; o.w = a[3] + bv.w;
                *(float4*)&out[(size_t)point * 96 + ct * 16 + q * 4] = o;
            }
        }
    }
}

// ---------------------------------------------------------------- fused attention
// R6 block shape (192 thr = 2 points; best measured occupancy/latency mix)
// + R8 conflict fixes: vs pitch 100 (row-start granule 25e mod 8 sweeps all 8
// float4 banksets), fold remap e2 = t2&15.
__global__ __launch_bounds__(192) void attn_kernel(
    const ushort* __restrict__ qbf, const ushort* __restrict__ kv,
    const float* __restrict__ xyz, const int* __restrict__ index_1,
    const ushort* __restrict__ rq, const ushort* __restrict__ rk,
    const ushort* __restrict__ rv, const float* __restrict__ mn,
    const float* __restrict__ shiftp, ushort* xout, int n) {
    __shared__ float qs[2][96];
    __shared__ float vs[2][16][100];
    __shared__ float smw[2][6][16];
    __shared__ int ridx[2][16][3];

    const int s = threadIdx.x / 96;
    const int tp = threadIdx.x - s * 96;
    const int p = blockIdx.x * 2 + s;
    const bool active = p < n;
    const float shift = shiftp[0];

    const int h = tp >> 4;  // 0..5
    const int e = tp & 15;

    int jd = 0;
    if (active) jd = index_1[(size_t)p * 16 + e];

    // ---- rel quantized index (48 thr/point) + q row unpack (48 thr/point)
    if (active && tp < 48) {
        const int c = tp >> 4;
        const float mnc = mn[c];
        float xi = floorf(fmodf(xyz[3 * p + c] - mnc + shift, 4.0f) * 4.0f);
        float xj = floorf(fmodf(xyz[3 * jd + c] - mnc + shift, 4.0f) * 4.0f);
        ridx[s][e][c] = (int)(xi - xj) + 15;
        uint qu = *(const uint*)(qbf + (size_t)p * 96 + tp * 2);
        qs[s][tp * 2] = bl(qu);
        qs[s][tp * 2 + 1] = bh(qu);
    }

    // ---- gather: k fragment into regs, v fragment into LDS
    float4 k0, k1, k2, k3;
    k0 = k1 = k2 = k3 = make_float4(0.f, 0.f, 0.f, 0.f);
    if (active) {
        const ushort* row = kv + (size_t)jd * 192;
        uint4 ka = *(const uint4*)(row + h * 16);
        uint4 kb = *(const uint4*)(row + h * 16 + 8);
        uint4 va = *(const uint4*)(row + 96 + h * 16);
        uint4 vb = *(const uint4*)(row + 96 + h * 16 + 8);
        k0 = make_float4(bl(ka.x), bh(ka.x), bl(ka.y), bh(ka.y));
        k1 = make_float4(bl(ka.z), bh(ka.z), bl(ka.w), bh(ka.w));
        k2 = make_float4(bl(kb.x), bh(kb.x), bl(kb.y), bh(kb.y));
        k3 = make_float4(bl(kb.z), bh(kb.z), bl(kb.w), bh(kb.w));
        *(float4*)&vs[s][e][h * 16 + 0]  = make_float4(bl(va.x), bh(va.x), bl(va.y), bh(va.y));
        *(float4*)&vs[s][e][h * 16 + 4]  = make_float4(bl(va.z), bh(va.z), bl(va.w), bh(va.w));
        *(float4*)&vs[s][e][h * 16 + 8]  = make_float4(bl(vb.x), bh(vb.x), bl(vb.y), bh(vb.y));
        *(float4*)&vs[s][e][h * 16 + 12] = make_float4(bl(vb.z), bh(vb.z), bl(vb.w), bh(vb.w));
    }
    __syncthreads();

    // ---- fold table-v bias into vs: e2 = t2&15 so a 16-lane group sweeps 16
    // distinct rows (pitch 100 -> row starts span all 8 float4 offsets)
    if (active) {
#pragma unroll
        for (int it = 0; it < 2; it++) {
            int t2 = tp + 96 * it;
            int e2 = t2 & 15, c8 = t2 >> 4;  // c8 in 0..11
            int i0 = ridx[s][e2][0], i1 = ridx[s][e2][1], i2 = ridx[s][e2][2];
            uint4 u0 = *(const uint4*)(rv + i0 * 96 + c8 * 8);
            uint4 u1 = *(const uint4*)(rv + (64 + i1) * 96 + c8 * 8);
            uint4 u2 = *(const uint4*)(rv + (128 + i2) * 96 + c8 * 8);
            float4* vp = (float4*)&vs[s][e2][c8 * 8];
            float4 a0 = vp[0], a1 = vp[1];
            a0.x += bl(u0.x) + bl(u1.x) + bl(u2.x);
            a0.y += bh(u0.x) + bh(u1.x) + bh(u2.x);
            a0.z += bl(u0.y) + bl(u1.y) + bl(u2.y);
            a0.w += bh(u0.y) + bh(u1.y) + bh(u2.y);
            a1.x += bl(u0.z) + bl(u1.z) + bl(u2.z);
            a1.y += bh(u0.z) + bh(u1.z) + bh(u2.z);
            a1.z += bl(u0.w) + bl(u1.w) + bl(u2.w);
            a1.w += bh(u0.w) + bh(u1.w) + bh(u2.w);
            vp[0] = a0; vp[1] = a1;
        }
    }

    // ---- score: qk + bf16 bias tables (per-c batched loads), shuffle softmax
    {
        const float4* q4 = (const float4*)&qs[s][h * 16];
        float4 qa = q4[0], qb = q4[1], qc = q4[2], qd = q4[3];
        float a = dot4(qa, k0) + dot4(qb, k1) + dot4(qc, k2) + dot4(qd, k3);
#pragma unroll
        for (int c = 0; c < 3; c++) {
            int idx = ridx[s][e][c];
            const uint4* tq4 = (const uint4*)(rq + (c * 64 + idx) * 96 + h * 16);
            const uint4* tk4 = (const uint4*)(rk + (c * 64 + idx) * 96 + h * 16);
            uint4 t0 = tq4[0], t1 = tq4[1];
            a += qa.x * bl(t0.x) + qa.y * bh(t0.x) + qa.z * bl(t0.y) + qa.w * bh(t0.y) +
                 qb.x * bl(t0.z) + qb.y * bh(t0.z) + qb.z * bl(t0.w) + qb.w * bh(t0.w) +
                 qc.x * bl(t1.x) + qc.y * bh(t1.x) + qc.z * bl(t1.y) + qc.w * bh(t1.y) +
                 qd.x * bl(t1.z) + qd.y * bh(t1.z) + qd.z * bl(t1.w) + qd.w * bh(t1.w);
            uint4 u0 = tk4[0], u1 = tk4[1];
            a += k0.x * bl(u0.x) + k0.y * bh(u0.x) + k0.z * bl(u0.y) + k0.w * bh(u0.y) +
                 k1.x * bl(u0.z) + k1.y * bh(u0.z) + k1.z * bl(u0.w) + k1.w * bh(u0.w) +
                 k2.x * bl(u1.x) + k2.y * bh(u1.x) + k2.z * bl(u1.y) + k2.w * bh(u1.y) +
                 k3.x * bl(u1.z) + k3.y * bh(u1.z) + k3.z * bl(u1.w) + k3.w * bh(u1.w);
        }
        float m = a;
#pragma unroll
        for (int off = 8; off >= 1; off >>= 1) m = fmaxf(m, __shfl_xor(m, off, 16));
        float ex = __expf(a - m);
        float sum = ex;
#pragma unroll
        for (int off = 8; off >= 1; off >>= 1) sum += __shfl_xor(sum, off, 16);
        if (active) smw[s][h][e] = ex / sum;
    }
    __syncthreads();

    // ---- output: pure LDS-FMA, emit bf16 x
    {
        float x = 0.f;
#pragma unroll
        for (int ee = 0; ee < 16; ee++) x += smw[s][h][ee] * vs[s][ee][tp];
        if (active) xout[(size_t)p * 96 + tp] = f2bf(x);  // xout aliases qbf: own row only
    }
}

// ---------------------------------------------------------------- launch
extern "C" void kernel_launch(void* const* d_in, const int* in_sizes, int n_in,
                              void* d_out, int out_size, void* d_ws, size_t ws_size,
                              hipStream_t stream) {
    const float* feats   = (const float*)d_in[0];
    const float* xyz     = (const float*)d_in[1];
    const int*   index_1 = (const int*)d_in[5];
    const float* shiftp  = (const float*)d_in[6];
    const float* W_qkv   = (const float*)d_in[7];
    const float* b_qkv   = (const float*)d_in[8];
    const float* table_q = (const float*)d_in[9];
    const float* table_k = (const float*)d_in[10];
    const float* table_v = (const float*)d_in[11];
    const float* W_proj  = (const float*)d_in[12];
    const float* b_proj  = (const float*)d_in[13];
    float* out = (float*)d_out;

    const int n = in_sizes[0] / 96;  // 50000

    float* w = (float*)d_ws;
    float*  mn     = w;                         // 16 floats (uint-min bits)
    ushort* qbf    = (ushort*)(w + 16);         // n*96 bf16
    ushort* kvbuf  = qbf + (size_t)n * 96;      // n*192 bf16
    ushort* xbuf   = qbf;  // alias: q[p] consumed by its own block before x[p] write
    ushort* wtqkv  = kvbuf + (size_t)n * 192;   // 27648 bf16
    ushort* wtproj = wtqkv + 27648;             // 9216 bf16
    ushort* rq     = wtproj + 9216;             // 18432 bf16 each
    ushort* rk     = rq + 18432;
    ushort* rv     = rk + 18432;

    const int GB = (n + 127) / 128;

    hipMemsetAsync(mn, 0xFF, 16 * sizeof(float), stream);  // +inf for unsigned min
    prep_kernel<<<256, 256, 0, stream>>>(xyz, n, W_qkv, W_proj, table_q, table_k,
                                         table_v, wtqkv, wtproj, rq, rk, rv,
                                         (uint*)mn);
    qkv_mfma_kernel<<<GB, 256, 0, stream>>>(feats, wtqkv, b_qkv, qbf, kvbuf, n);
    attn_kernel<<<(n + 1) / 2, 192, 0, stream>>>(qbf, kvbuf, xyz, index_1, rq, rk,
                                                 rv, mn, shiftp, xbuf, n);
    proj_mfma_kernel<<<GB, 256, 0, stream>>>(xbuf, wtproj, b_proj, out, n);
}

// Round 10
// 279.870 us; speedup vs baseline: 1.6669x; 1.0656x over previous
//
#include <hip/hip_runtime.h>
#include <math.h>

#define FLT_BIG 3.402823466e38f
typedef unsigned int uint;
typedef unsigned short ushort;
typedef __attribute__((ext_vector_type(8))) short short8;   // 8 bf16 (4 VGPRs)
typedef __attribute__((ext_vector_type(4))) float floatx4;  // MFMA C/D frag

__device__ inline float bl(uint u) { return __uint_as_float(u << 16); }
__device__ inline float bh(uint u) { return __uint_as_float(u & 0xffff0000u); }
__device__ inline ushort f2bf(float f) {  // RNE
    uint u = __float_as_uint(f);
    return (ushort)((u + 0x7fffu + ((u >> 16) & 1u)) >> 16);
}
__device__ inline float dot4(float4 a, float4 b) {
    return a.x * b.x + a.y * b.y + a.z * b.z + a.w * b.w;
}

// ---------------------------------------------------------------- prep
// Fused: xyz min-reduce (unsigned atomicMin on float bits; mn pre-set to
// 0xFFFFFFFF via hipMemsetAsync), table permute [idx][hd][c]->[c][idx][hd]
// bf16, W transposes -> bf16 WT[outcol][k].
__global__ void prep_kernel(const float* __restrict__ xyz, int n,
                            const float* __restrict__ W_qkv,
                            const float* __restrict__ W_proj,
                            const float* __restrict__ tq, const float* __restrict__ tk,
                            const float* __restrict__ tv,
                            ushort* __restrict__ wtqkv, ushort* __restrict__ wtproj,
                            ushort* __restrict__ rq, ushort* __restrict__ rk,
                            ushort* __restrict__ rv, uint* __restrict__ mnbits) {
    int tid = blockIdx.x * 256 + threadIdx.x;
    if (tid < 18432) {  // tables: 3*64*96 -> bf16
        int c = tid / 6144, rem = tid - c * 6144;
        int idx = rem / 96, hd = rem - idx * 96;
        int src = (idx * 96 + hd) * 3 + c;
        rq[tid] = f2bf(tq[src]);
        rk[tid] = f2bf(tk[src]);
        rv[tid] = f2bf(tv[src]);
    }
    if (tid < 27648) {  // WT_qkv[j][d] = W_qkv[d][j], j over 288
        int j = tid / 96, d = tid - j * 96;
        wtqkv[tid] = f2bf(W_qkv[d * 288 + j]);
    }
    if (tid < 9216) {  // WT_proj[j][d] = W_proj[d][j]
        int j = tid / 96, d = tid - j * 96;
        wtproj[tid] = f2bf(W_proj[d * 96 + j]);
    }
    // min(xyz) — xyz >= 0 so float bits are monotone under unsigned compare
    float m0 = FLT_BIG, m1 = FLT_BIG, m2 = FLT_BIG;
    for (int i = tid; i < n; i += gridDim.x * 256) {
        m0 = fminf(m0, xyz[3 * i + 0]);
        m1 = fminf(m1, xyz[3 * i + 1]);
        m2 = fminf(m2, xyz[3 * i + 2]);
    }
#pragma unroll
    for (int off = 32; off > 0; off >>= 1) {
        m0 = fminf(m0, __shfl_down(m0, off));
        m1 = fminf(m1, __shfl_down(m1, off));
        m2 = fminf(m2, __shfl_down(m2, off));
    }
    if ((threadIdx.x & 63) == 0) {
        atomicMin(&mnbits[0], __float_as_uint(m0));
        atomicMin(&mnbits[1], __float_as_uint(m1));
        atomicMin(&mnbits[2], __float_as_uint(m2));
    }
}

// ---------------------------------------------------------------- QKV MFMA GEMM
// D = W·feats (swapped operands): D[row=q*4+r][col=m] -> lane holds 4
// consecutive out cols of point m -> packed ushort4 stores, no LDS epilogue.
__global__ __launch_bounds__(256) void qkv_mfma_kernel(
    const float* __restrict__ feats, const ushort* __restrict__ WT,
    const float* __restrict__ bias, ushort* __restrict__ qout,
    ushort* __restrict__ kvout, int n) {
    __shared__ ushort As[128 * 104];  // pitch 104 ushort
    const int t = threadIdx.x;
    const int wave = t >> 6, lane = t & 63;
    const int m = lane & 15, q = lane >> 4;
    const int row0 = blockIdx.x * 128;

    const float4* F4 = (const float4*)feats;
    for (int i = t; i < 3072; i += 256) {
        int r = i / 24, c4 = i - r * 24;
        int gr = row0 + r;
        if (gr > n - 1) gr = n - 1;
        float4 f = F4[(size_t)gr * 24 + c4];
        ushort4 u;
        u.x = f2bf(f.x); u.y = f2bf(f.y); u.z = f2bf(f.z); u.w = f2bf(f.w);
        *(ushort4*)&As[r * 104 + c4 * 4] = u;
    }
    __syncthreads();

    short8 ff[2][3];
#pragma unroll
    for (int g = 0; g < 2; g++)
#pragma unroll
        for (int k = 0; k < 3; k++)
            ff[g][k] = *(const short8*)&As[(wave * 32 + g * 16 + m) * 104 + k * 32 + q * 8];

    const int p0 = row0 + wave * 32 + m;
    const int p1 = p0 + 16;

#pragma unroll
    for (int ch = 0; ch < 3; ch++) {
#pragma unroll
        for (int ct = 0; ct < 6; ct++) {
            floatx4 acc0 = (floatx4){0.f, 0.f, 0.f, 0.f};
            floatx4 acc1 = (floatx4){0.f, 0.f, 0.f, 0.f};
            const ushort* wb = WT + ((size_t)(ch * 96 + ct * 16 + m)) * 96 + q * 8;
#pragma unroll
            for (int k = 0; k < 3; k++) {
                short8 wf = *(const short8*)(wb + k * 32);
                acc0 = __builtin_amdgcn_mfma_f32_16x16x32_bf16(wf, ff[0][k], acc0, 0, 0, 0);
                acc1 = __builtin_amdgcn_mfma_f32_16x16x32_bf16(wf, ff[1][k], acc1, 0, 0, 0);
            }
            float4 bv = *(const float4*)&bias[ch * 96 + ct * 16 + q * 4];
            const float sc = (ch == 0) ? 0.25f : 1.0f;
#pragma unroll
            for (int g = 0; g < 2; g++) {
                int point = g ? p1 : p0;
                if (point < n) {
                    floatx4 a = g ? acc1 : acc0;
                    ushort4 u;
                    u.x = f2bf((a[0] + bv.x) * sc);
                    u.y = f2bf((a[1] + bv.y) * sc);
                    u.z = f2bf((a[2] + bv.z) * sc);
                    u.w = f2bf((a[3] + bv.w) * sc);
                    ushort* dst = (ch == 0)
                        ? qout + (size_t)point * 96 + ct * 16 + q * 4
                        : kvout + (size_t)point * 192 + ((ch == 2) ? 96 : 0) + ct * 16 + q * 4;
                    *(ushort4*)dst = u;
                }
            }
        }
    }
}

// ---------------------------------------------------------------- proj MFMA GEMM
__global__ __launch_bounds__(256) void proj_mfma_kernel(
    const ushort* __restrict__ X, const ushort* __restrict__ WT,
    const float* __restrict__ bias, float* __restrict__ out, int n) {
    const int wave = threadIdx.x >> 6, lane = threadIdx.x & 63;
    const int m = lane & 15, q = lane >> 4;
    const int row0 = blockIdx.x * 128 + wave * 32;
    if (row0 >= n) return;
    int r0 = row0 + m;      if (r0 > n - 1) r0 = n - 1;
    int r1 = row0 + 16 + m; if (r1 > n - 1) r1 = n - 1;

    short8 xf[2][3];
#pragma unroll
    for (int k = 0; k < 3; k++) {
        xf[0][k] = *(const short8*)(X + (size_t)r0 * 96 + k * 32 + q * 8);
        xf[1][k] = *(const short8*)(X + (size_t)r1 * 96 + k * 32 + q * 8);
    }

#pragma unroll
    for (int ct = 0; ct < 6; ct++) {
        floatx4 acc0 = (floatx4){0.f, 0.f, 0.f, 0.f};
        floatx4 acc1 = (floatx4){0.f, 0.f, 0.f, 0.f};
        const ushort* wb = WT + ((size_t)(ct * 16 + m)) * 96 + q * 8;
#pragma unroll
        for (int k = 0; k < 3; k++) {
            short8 wf = *(const short8*)(wb + k * 32);
            acc0 = __builtin_amdgcn_mfma_f32_16x16x32_bf16(wf, xf[0][k], acc0, 0, 0, 0);
            acc1 = __builtin_amdgcn_mfma_f32_16x16x32_bf16(wf, xf[1][k], acc1, 0, 0, 0);
        }
        float4 bv = *(const float4*)&bias[ct * 16 + q * 4];
#pragma unroll
        for (int g = 0; g < 2; g++) {
            int point = row0 + g * 16 + m;
            if (point < n) {
                floatx4 a = g ? acc1 : acc0;
                float4 o;
                o.x = a[0] + bv.x; o.y = a[1] + bv.y;
                o.z = a[2] + bv.z; o.w = a[3] + bv.w;
                *(float4*)&out[(size_t)point * 96 + ct * 16 + q * 4] = o;
            }
        }
    }
}

// ---------------------------------------------------------------- fused attention
// Best-of-both: vs pitch 100 (v-store phase <=2-way banks, R8/R9) + R6 fold
// mapping e2=t2/12 (consecutive lanes sweep one table row -> coalesced rv).
__global__ __launch_bounds__(192) void attn_kernel(
    const ushort* __restrict__ qbf, const ushort* __restrict__ kv,
    const float* __restrict__ xyz, const int* __restrict__ index_1,
    const ushort* __restrict__ rq, const ushort* __restrict__ rk,
    const ushort* __restrict__ rv, const float* __restrict__ mn,
    const float* __restrict__ shiftp, ushort* xout, int n) {
    __shared__ float qs[2][96];
    __shared__ float vs[2][16][100];
    __shared__ float smw[2][6][16];
    __shared__ int ridx[2][16][3];

    const int s = threadIdx.x / 96;
    const int tp = threadIdx.x - s * 96;
    const int p = blockIdx.x * 2 + s;
    const bool active = p < n;
    const float shift = shiftp[0];

    const int h = tp >> 4;  // 0..5
    const int e = tp & 15;

    int jd = 0;
    if (active) jd = index_1[(size_t)p * 16 + e];

    // ---- rel quantized index (48 thr/point) + q row unpack (48 thr/point)
    if (active && tp < 48) {
        const int c = tp >> 4;
        const float mnc = mn[c];
        float xi = floorf(fmodf(xyz[3 * p + c] - mnc + shift, 4.0f) * 4.0f);
        float xj = floorf(fmodf(xyz[3 * jd + c] - mnc + shift, 4.0f) * 4.0f);
        ridx[s][e][c] = (int)(xi - xj) + 15;
        uint qu = *(const uint*)(qbf + (size_t)p * 96 + tp * 2);
        qs[s][tp * 2] = bl(qu);
        qs[s][tp * 2 + 1] = bh(qu);
    }

    // ---- gather: k fragment into regs, v fragment into LDS
    float4 k0, k1, k2, k3;
    k0 = k1 = k2 = k3 = make_float4(0.f, 0.f, 0.f, 0.f);
    if (active) {
        const ushort* row = kv + (size_t)jd * 192;
        uint4 ka = *(const uint4*)(row + h * 16);
        uint4 kb = *(const uint4*)(row + h * 16 + 8);
        uint4 va = *(const uint4*)(row + 96 + h * 16);
        uint4 vb = *(const uint4*)(row + 96 + h * 16 + 8);
        k0 = make_float4(bl(ka.x), bh(ka.x), bl(ka.y), bh(ka.y));
        k1 = make_float4(bl(ka.z), bh(ka.z), bl(ka.w), bh(ka.w));
        k2 = make_float4(bl(kb.x), bh(kb.x), bl(kb.y), bh(kb.y));
        k3 = make_float4(bl(kb.z), bh(kb.z), bl(kb.w), bh(kb.w));
        *(float4*)&vs[s][e][h * 16 + 0]  = make_float4(bl(va.x), bh(va.x), bl(va.y), bh(va.y));
        *(float4*)&vs[s][e][h * 16 + 4]  = make_float4(bl(va.z), bh(va.z), bl(va.w), bh(va.w));
        *(float4*)&vs[s][e][h * 16 + 8]  = make_float4(bl(vb.x), bh(vb.x), bl(vb.y), bh(vb.y));
        *(float4*)&vs[s][e][h * 16 + 12] = make_float4(bl(vb.z), bh(vb.z), bl(vb.w), bh(vb.w));
    }
    __syncthreads();

    // ---- fold table-v bias into vs: e2=t2/12 -> 12 consecutive lanes sweep
    // one table row's columns (coalesced rv loads, the R6-measured win)
    if (active) {
#pragma unroll
        for (int it = 0; it < 2; it++) {
            int t2 = tp + 96 * it;
            int e2 = t2 / 12, c8 = t2 - e2 * 12;  // c8 in 0..11
            int i0 = ridx[s][e2][0], i1 = ridx[s][e2][1], i2 = ridx[s][e2][2];
            uint4 u0 = *(const uint4*)(rv + i0 * 96 + c8 * 8);
            uint4 u1 = *(const uint4*)(rv + (64 + i1) * 96 + c8 * 8);
            uint4 u2 = *(const uint4*)(rv + (128 + i2) * 96 + c8 * 8);
            float4* vp = (float4*)&vs[s][e2][c8 * 8];
            float4 a0 = vp[0], a1 = vp[1];
            a0.x += bl(u0.x) + bl(u1.x) + bl(u2.x);
            a0.y += bh(u0.x) + bh(u1.x) + bh(u2.x);
            a0.z += bl(u0.y) + bl(u1.y) + bl(u2.y);
            a0.w += bh(u0.y) + bh(u1.y) + bh(u2.y);
            a1.x += bl(u0.z) + bl(u1.z) + bl(u2.z);
            a1.y += bh(u0.z) + bh(u1.z) + bh(u2.z);
            a1.z += bl(u0.w) + bl(u1.w) + bl(u2.w);
            a1.w += bh(u0.w) + bh(u1.w) + bh(u2.w);
            vp[0] = a0; vp[1] = a1;
        }
    }

    // ---- score: qk + bf16 bias tables (per-c batched loads), shuffle softmax
    {
        const float4* q4 = (const float4*)&qs[s][h * 16];
        float4 qa = q4[0], qb = q4[1], qc = q4[2], qd = q4[3];
        float a = dot4(qa, k0) + dot4(qb, k1) + dot4(qc, k2) + dot4(qd, k3);
#pragma unroll
        for (int c = 0; c < 3; c++) {
            int idx = ridx[s][e][c];
            const uint4* tq4 = (const uint4*)(rq + (c * 64 + idx) * 96 + h * 16);
            const uint4* tk4 = (const uint4*)(rk + (c * 64 + idx) * 96 + h * 16);
            uint4 t0 = tq4[0], t1 = tq4[1];
            a += qa.x * bl(t0.x) + qa.y * bh(t0.x) + qa.z * bl(t0.y) + qa.w * bh(t0.y) +
                 qb.x * bl(t0.z) + qb.y * bh(t0.z) + qb.z * bl(t0.w) + qb.w * bh(t0.w) +
                 qc.x * bl(t1.x) + qc.y * bh(t1.x) + qc.z * bl(t1.y) + qc.w * bh(t1.y) +
                 qd.x * bl(t1.z) + qd.y * bh(t1.z) + qd.z * bl(t1.w) + qd.w * bh(t1.w);
            uint4 u0 = tk4[0], u1 = tk4[1];
            a += k0.x * bl(u0.x) + k0.y * bh(u0.x) + k0.z * bl(u0.y) + k0.w * bh(u0.y) +
                 k1.x * bl(u0.z) + k1.y * bh(u0.z) + k1.z * bl(u0.w) + k1.w * bh(u0.w) +
                 k2.x * bl(u1.x) + k2.y * bh(u1.x) + k2.z * bl(u1.y) + k2.w * bh(u1.y) +
                 k3.x * bl(u1.z) + k3.y * bh(u1.z) + k3.z * bl(u1.w) + k3.w * bh(u1.w);
        }
        float m = a;
#pragma unroll
        for (int off = 8; off >= 1; off >>= 1) m = fmaxf(m, __shfl_xor(m, off, 16));
        float ex = __expf(a - m);
        float sum = ex;
#pragma unroll
        for (int off = 8; off >= 1; off >>= 1) sum += __shfl_xor(sum, off, 16);
        if (active) smw[s][h][e] = ex / sum;
    }
    __syncthreads();

    // ---- output: pure LDS-FMA, emit bf16 x
    {
        float x = 0.f;
#pragma unroll
        for (int ee = 0; ee < 16; ee++) x += smw[s][h][ee] * vs[s][ee][tp];
        if (active) xout[(size_t)p * 96 + tp] = f2bf(x);  // xout aliases qbf: own row only
    }
}

// ---------------------------------------------------------------- launch
extern "C" void kernel_launch(void* const* d_in, const int* in_sizes, int n_in,
                              void* d_out, int out_size, void* d_ws, size_t ws_size,
                              hipStream_t stream) {
    const float* feats   = (const float*)d_in[0];
    const float* xyz     = (const float*)d_in[1];
    const int*   index_1 = (const int*)d_in[5];
    const float* shiftp  = (const float*)d_in[6];
    const float* W_qkv   = (const float*)d_in[7];
    const float* b_qkv   = (const float*)d_in[8];
    const float* table_q = (const float*)d_in[9];
    const float* table_k = (const float*)d_in[10];
    const float* table_v = (const float*)d_in[11];
    const float* W_proj  = (const float*)d_in[12];
    const float* b_proj  = (const float*)d_in[13];
    float* out = (float*)d_out;

    const int n = in_sizes[0] / 96;  // 50000

    float* w = (float*)d_ws;
    float*  mn     = w;                         // 16 floats (uint-min bits)
    ushort* qbf    = (ushort*)(w + 16);         // n*96 bf16
    ushort* kvbuf  = qbf + (size_t)n * 96;      // n*192 bf16
    ushort* xbuf   = qbf;  // alias: q[p] consumed by its own block before x[p] write
    ushort* wtqkv  = kvbuf + (size_t)n * 192;   // 27648 bf16
    ushort* wtproj = wtqkv + 27648;             // 9216 bf16
    ushort* rq     = wtproj + 9216;             // 18432 bf16 each
    ushort* rk     = rq + 18432;
    ushort* rv     = rk + 18432;

    const int GB = (n + 127) / 128;

    hipMemsetAsync(mn, 0xFF, 16 * sizeof(float), stream);  // +inf for unsigned min
    prep_kernel<<<256, 256, 0, stream>>>(xyz, n, W_qkv, W_proj, table_q, table_k,
                                         table_v, wtqkv, wtproj, rq, rk, rv,
                                         (uint*)mn);
    qkv_mfma_kernel<<<GB, 256, 0, stream>>>(feats, wtqkv, b_qkv, qbf, kvbuf, n);
    attn_kernel<<<(n + 1) / 2, 192, 0, stream>>>(qbf, kvbuf, xyz, index_1, rq, rk,
                                                 rv, mn, shiftp, xbuf, n);
    proj_mfma_kernel<<<GB, 256, 0, stream>>>(xbuf, wtproj, b_proj, out, n);
}